// Round 2
// baseline (1431.521 us; speedup 1.0000x reference)
//
#include <hip/hip_runtime.h>

#define CPG 8
#define NGRP 32
#define NB 16
#define HW 3136
#define HW2 1568     // HW in float2 units
#define N2 36
#define N3 120

// index of pair (i,j), i<=j, in np.triu_indices(8) order
__host__ __device__ constexpr int idx2(int i, int j) {
    return i * CPG - i * (i - 1) / 2 + (j - i);
}
// index of triple (a,b,c), a<=b<=c, lexicographic
__host__ __device__ constexpr int idx3(int a, int b, int c) {
    int base = 0;
    for (int t = 0; t < a; ++t) { int m = CPG - t; base += m * (m + 1) / 2; }
    for (int t = a; t < b; ++t) base += CPG - t;
    return base + (c - b);
}

// LDS weight table: wt[f][o] transposed, f in [0,164): 0-7 deg1, 8-43 deg2,
// 44-163 deg3; slot 164 = summed bias. One ds_read_b128 = 4 o-weights/feature.
__global__ __launch_bounds__(256, 4) void hoaf_kernel(
    const float* __restrict__ x,
    const float* __restrict__ w1, const float* __restrict__ b1,
    const float* __restrict__ w2, const float* __restrict__ b2,
    const float* __restrict__ w3, const float* __restrict__ b3,
    float* __restrict__ out)
{
    __shared__ __align__(16) float wt[(164 + 1) * 4];

    const int tid   = threadIdx.x;
    const int chunk = blockIdx.x;          // 0..1 pixel halves
    const int g     = blockIdx.y;          // 0..31
    const int b     = blockIdx.z >> 1;     // 0..15
    const int obase = (blockIdx.z & 1) * 4; // output-channel split

    // one-time weight staging (transposed)
    for (int idx = tid; idx < 656; idx += 256) {
        const int o = idx & 3, f = idx >> 2;
        const int ch = g * CPG + obase + o;
        float v;
        if (f < 8)       v = w1[ch * CPG + f];
        else if (f < 44) v = w2[ch * N2 + (f - 8)];
        else             v = w3[ch * N3 + (f - 44)];
        wt[idx] = v;
    }
    if (tid < 4) {
        const int ch = g * CPG + obase + tid;
        wt[656 + tid] = b1[ch] + b2[ch] + b3[ch];
    }
    __syncthreads();

    const size_t base = ((size_t)(b * NGRP + g) * CPG) * HW;
    const float2* x2 = (const float2*)(x + base);
    float2*       o2 = (float2*)(out + base) + (size_t)obase * HW2;

#pragma unroll 1
    for (int q = tid + chunk * 256; q < HW2; q += 512) {
        float2 xv[CPG];
#pragma unroll
        for (int c = 0; c < CPG; ++c) xv[c] = x2[(size_t)c * HW2 + q];

        const float4 bv = *reinterpret_cast<const float4*>(&wt[164 * 4]);
        float2 acc[4];
        acc[0] = {bv.x, bv.x}; acc[1] = {bv.y, bv.y};
        acc[2] = {bv.z, bv.z}; acc[3] = {bv.w, bv.w};

        // degree 1
#pragma unroll
        for (int k = 0; k < CPG; ++k) {
            const float4 wv = *reinterpret_cast<const float4*>(&wt[k * 4]);
            acc[0].x += wv.x * xv[k].x; acc[0].y += wv.x * xv[k].y;
            acc[1].x += wv.y * xv[k].x; acc[1].y += wv.y * xv[k].y;
            acc[2].x += wv.z * xv[k].x; acc[2].y += wv.z * xv[k].y;
            acc[3].x += wv.w * xv[k].x; acc[3].y += wv.w * xv[k].y;
        }

        // degree 2 & 3: pair product feeds its triples
#pragma unroll
        for (int i = 0; i < CPG; ++i) {
#pragma unroll
            for (int j = i; j < CPG; ++j) {
                float2 p;
                p.x = xv[i].x * xv[j].x;
                p.y = xv[i].y * xv[j].y;
                {
                    const float4 wv = *reinterpret_cast<const float4*>(&wt[(8 + idx2(i, j)) * 4]);
                    acc[0].x += wv.x * p.x; acc[0].y += wv.x * p.y;
                    acc[1].x += wv.y * p.x; acc[1].y += wv.y * p.y;
                    acc[2].x += wv.z * p.x; acc[2].y += wv.z * p.y;
                    acc[3].x += wv.w * p.x; acc[3].y += wv.w * p.y;
                }
#pragma unroll
                for (int a = 0; a <= i; ++a) {
                    float2 t;
                    t.x = xv[a].x * p.x;
                    t.y = xv[a].y * p.y;
                    const float4 wv = *reinterpret_cast<const float4*>(&wt[(44 + idx3(a, i, j)) * 4]);
                    acc[0].x += wv.x * t.x; acc[0].y += wv.x * t.y;
                    acc[1].x += wv.y * t.x; acc[1].y += wv.y * t.y;
                    acc[2].x += wv.z * t.x; acc[2].y += wv.z * t.y;
                    acc[3].x += wv.w * t.x; acc[3].y += wv.w * t.y;
                }
            }
        }

#pragma unroll
        for (int o = 0; o < 4; ++o) o2[(size_t)o * HW2 + q] = acc[o];
    }
}

extern "C" void kernel_launch(void* const* d_in, const int* in_sizes, int n_in,
                              void* d_out, int out_size, void* d_ws, size_t ws_size,
                              hipStream_t stream) {
    const float* x  = (const float*)d_in[0];
    const float* w1 = (const float*)d_in[1];
    const float* b1 = (const float*)d_in[2];
    const float* w2 = (const float*)d_in[3];
    const float* b2 = (const float*)d_in[4];
    const float* w3 = (const float*)d_in[5];
    const float* b3 = (const float*)d_in[6];
    float* out = (float*)d_out;

    dim3 grid(2, NGRP, NB * 2);
    dim3 block(256);
    hoaf_kernel<<<grid, block, 0, stream>>>(x, w1, b1, w2, b2, w3, b3, out);
}